// Round 3
// baseline (71.356 us; speedup 1.0000x reference)
//
#include <hip/hip_runtime.h>

#define A_DIM 1024
#define B_DIM 1024

typedef __attribute__((ext_vector_type(8))) short bfrag8;
typedef __attribute__((ext_vector_type(4))) float facc4;

__device__ __forceinline__ unsigned short f2bf(float f) {
    unsigned u = __float_as_uint(f);
    u = (u + 0x7FFFu + ((u >> 16) & 1u)) >> 16;
    return (unsigned short)u;
}
__device__ __forceinline__ unsigned cvtpk(float lo, float hi) {
    unsigned r;
    asm("v_cvt_pk_bf16_f32 %0, %1, %2" : "=v"(r) : "v"(lo), "v"(hi));
    return r;
}

// ---------------------------------------------------------------------------
// Kernel 1: ha[a][d] = b1e[d] + sum_k nodes_a[a][k] * Wa[k][d]
//           hb[b][d] =          sum_k nodes_b[b][k] * Wb[k][d]
// ---------------------------------------------------------------------------
__global__ __launch_bounds__(256) void prep_kernel(
    const float* __restrict__ na, const float* __restrict__ nb,
    const float* __restrict__ W1e, const float* __restrict__ b1e,
    float* __restrict__ ha, float* __restrict__ hb)
{
    int idx = blockIdx.x * 256 + threadIdx.x;   // 0..32767
    int half = idx >> 14;                       // 0 = a-side, 1 = b-side
    int r = (idx >> 4) & 1023;
    int d = idx & 15;
    const float* x = (half ? nb : na) + r * 32;
    const float* W = W1e + (half ? 64 * 16 : 32 * 16) + d;
    float acc = half ? 0.f : b1e[d];
    #pragma unroll
    for (int k = 0; k < 32; ++k) acc += x[k] * W[k * 16];
    (half ? hb : ha)[r * 16 + d] = acc;
}

// ---------------------------------------------------------------------------
// Kernel 2: fused edge MLP via MFMA, no LDS staging.
// Block = 1024 threads = 16 waves. Block owns 64 b (bg) x 32 a (at).
// Wave w handles a = abase + w*2 + i (i=0,1); 4 mt tiles of 16 edges.
// B-fragment loaded DIRECT from global: lane (n,g) reads 8 f32 of edge
// (bbase+mt*16+n) at k=g*8 (the 64 lanes tile a contiguous 2KB exactly),
// converted to bf16 in-register. C-in = ha[a] + hb[b] (global, L1-hot).
// C/D layout: col = lane&15 (edge), row = (lane>>4)*4 + reg (d).
// ---------------------------------------------------------------------------
__global__ __launch_bounds__(1024, 8) void edge_kernel(
    const float* __restrict__ E, const float* __restrict__ W1e,
    const float* __restrict__ W2e, const float* __restrict__ b2e,
    const float* __restrict__ ha, const float* __restrict__ hb,
    float* __restrict__ el_out, float* __restrict__ suma_p,
    float* __restrict__ sumb_p)
{
    __shared__ __align__(16) float sb[8 * 64 * 16];   // 32 KB, sumb combine only
    const int tid  = threadIdx.x;
    const int lane = tid & 63;
    const int w    = tid >> 6;              // 0..15
    const int n    = lane & 15;             // edge-in-tile / weight d-col
    const int g    = lane >> 4;             // 0..3  k-chunk / d-row group
    const int bg   = blockIdx.x;            // 0..15
    const int at   = blockIdx.y;            // 0..31
    const int bbase = bg * 64;
    const int abase = at * 32;

    // persistent fragments (weights transposed: A[m][k] = W[k][m])
    bfrag8 w1f, w2f;
    #pragma unroll
    for (int t = 0; t < 8; ++t) {
        w1f[t] = (short)f2bf(W1e[(g * 8 + t) * 16 + n]);
        w2f[t] = (g < 2) ? (short)f2bf(W2e[(g * 8 + t) * 16 + n]) : (short)0;
    }
    facc4 b2f = *(const facc4*)&b2e[g * 4];

    facc4 sumbA[4];
    #pragma unroll
    for (int mt = 0; mt < 4; ++mt) sumbA[mt] = facc4{0.f, 0.f, 0.f, 0.f};

    #pragma unroll
    for (int i = 0; i < 2; ++i) {
        const int a = abase + w * 2 + i;
        facc4 haf = *(const facc4*)&ha[a * 16 + g * 4];
        facc4 ssum = facc4{0.f, 0.f, 0.f, 0.f};

        #pragma unroll
        for (int mt = 0; mt < 4; ++mt) {
            // direct-global B-fragment (2KB contiguous per wave per mt)
            const float* ep = E + ((size_t)a * B_DIM + bbase + mt * 16 + n) * 32 + g * 8;
            float4 lo = *(const float4*)ep;
            float4 hi = *(const float4*)(ep + 4);
            union { unsigned u[4]; bfrag8 s; } ef;
            ef.u[0] = cvtpk(lo.x, lo.y); ef.u[1] = cvtpk(lo.z, lo.w);
            ef.u[2] = cvtpk(hi.x, hi.y); ef.u[3] = cvtpk(hi.z, hi.w);

            facc4 hbf = *(const facc4*)&hb[(bbase + mt * 16 + n) * 16 + g * 4];
            facc4 h = __builtin_amdgcn_mfma_f32_16x16x32_bf16(
                w1f, ef.s, haf + hbf, 0, 0, 0);
            h.x = fmaxf(h.x, 0.f); h.y = fmaxf(h.y, 0.f);
            h.z = fmaxf(h.z, 0.f); h.w = fmaxf(h.w, 0.f);

            // transpose relu(h) (row=d,col=edge) -> layer2 B-frag:
            // lane (n,g) needs d in [8g,8g+8) of edge n, from lanes
            // n+32g (d=8g..8g+4) and n+32g+16 (d=8g+4..8g+8)
            const int sl = (n + g * 32) & 63;
            const int sh = (n + g * 32 + 16) & 63;
            float v0 = __shfl(h.x, sl), v1 = __shfl(h.y, sl);
            float v2 = __shfl(h.z, sl), v3 = __shfl(h.w, sl);
            float u0 = __shfl(h.x, sh), u1 = __shfl(h.y, sh);
            float u2 = __shfl(h.z, sh), u3 = __shfl(h.w, sh);
            union { unsigned u[4]; bfrag8 s; } bb;
            bb.u[0] = cvtpk(v0, v1); bb.u[1] = cvtpk(v2, v3);
            bb.u[2] = cvtpk(u0, u1); bb.u[3] = cvtpk(u2, u3);

            facc4 e = __builtin_amdgcn_mfma_f32_16x16x32_bf16(w2f, bb.s, b2f, 0, 0, 0);
            e.x = fmaxf(e.x, 0.f); e.y = fmaxf(e.y, 0.f);
            e.z = fmaxf(e.z, 0.f); e.w = fmaxf(e.w, 0.f);

            // coalesced store: lanes (g,n) cover 1KB contiguous per mt
            *(facc4*)&el_out[((size_t)a * B_DIM + bbase + mt * 16 + n) * 16 + g * 4] = e;
            sumbA[mt] += e;
            ssum += e;
        }
        // suma: butterfly over the 16 edge-cols (within 16-lane groups)
        #pragma unroll
        for (int m = 1; m <= 8; m <<= 1) {
            ssum.x += __shfl_xor(ssum.x, m);
            ssum.y += __shfl_xor(ssum.y, m);
            ssum.z += __shfl_xor(ssum.z, m);
            ssum.w += __shfl_xor(ssum.w, m);
        }
        if (n == 0)
            *(facc4*)&suma_p[((size_t)bg * A_DIM + a) * 16 + g * 4] = ssum;
    }

    // ---- combine sumb across 16 waves, two-stage, 32KB LDS ----
    __syncthreads();
    if (w >= 8) {
        #pragma unroll
        for (int mt = 0; mt < 4; ++mt)
            ((facc4*)sb)[((w - 8) * 64 + mt * 16 + n) * 4 + g] = sumbA[mt];
    }
    __syncthreads();
    if (w < 8) {
        #pragma unroll
        for (int mt = 0; mt < 4; ++mt) {
            sumbA[mt] += ((facc4*)sb)[(w * 64 + mt * 16 + n) * 4 + g];
            ((facc4*)sb)[(w * 64 + mt * 16 + n) * 4 + g] = sumbA[mt];
        }
    }
    __syncthreads();
    if (tid < 256) {
        const int bl = tid >> 2, q = tid & 3;
        facc4 s = facc4{0.f, 0.f, 0.f, 0.f};
        #pragma unroll
        for (int ww = 0; ww < 8; ++ww) s += ((facc4*)sb)[(ww * 64 + bl) * 4 + q];
        *(facc4*)&sumb_p[((size_t)at * B_DIM + bbase + bl) * 16 + q * 4] = s;
    }
}

// ---------------------------------------------------------------------------
// Kernel 3: node MLP for both sides, with inlined partial-sum reduction.
// 2048 rows, block = 8 rows x 32 cols. Threads j<16 of each row group
// reduce that row's latent-sum partials into LDS first.
// ---------------------------------------------------------------------------
__global__ __launch_bounds__(256) void node_kernel(
    const float* __restrict__ na, const float* __restrict__ nb,
    const float* __restrict__ suma_p, const float* __restrict__ sumb_p,
    const float* __restrict__ W1n, const float* __restrict__ b1n,
    const float* __restrict__ W2n, const float* __restrict__ b2n,
    float* __restrict__ out_a, float* __restrict__ out_b)
{
    __shared__ float W1_s[48 * 32];
    __shared__ float W2_s[32 * 32];
    __shared__ float hid_s[8][32];
    __shared__ float sx_s[8][16];
    int tid = threadIdx.x;
    for (int i = tid; i < 1536; i += 256) W1_s[i] = W1n[i];
    for (int i = tid; i < 1024; i += 256) W2_s[i] = W2n[i];
    int rlocal = tid >> 5;
    int r = blockIdx.x * 8 + rlocal;
    int j = tid & 31;
    int isb = (r >= 1024);
    int rr = isb ? r - 1024 : r;
    if (j < 16) {
        const float* P = isb ? sumb_p : suma_p;
        int np = isb ? 32 : 16;
        float acc = 0.f;
        for (int t = 0; t < np; ++t) acc += P[(size_t)t * 16384 + rr * 16 + j];
        sx_s[rlocal][j] = acc;
    }
    __syncthreads();
    const float* nx = (isb ? nb : na) + rr * 32;
    float acc = b1n[j];
    #pragma unroll
    for (int k = 0; k < 32; ++k) acc += nx[k] * W1_s[k * 32 + j];
    #pragma unroll
    for (int k = 0; k < 16; ++k) acc += sx_s[rlocal][k] * W1_s[(32 + k) * 32 + j];
    hid_s[rlocal][j] = fmaxf(acc, 0.f);
    __syncthreads();
    float acc2 = b2n[j];
    #pragma unroll
    for (int k = 0; k < 32; ++k) acc2 += hid_s[rlocal][k] * W2_s[k * 32 + j];
    (isb ? out_b : out_a)[rr * 32 + j] = fmaxf(acc2, 0.f);
}

extern "C" void kernel_launch(void* const* d_in, const int* in_sizes, int n_in,
                              void* d_out, int out_size, void* d_ws, size_t ws_size,
                              hipStream_t stream)
{
    const float* E   = (const float*)d_in[0];
    const float* na  = (const float*)d_in[1];
    const float* nb  = (const float*)d_in[2];
    const float* W1e = (const float*)d_in[3];
    const float* b1e = (const float*)d_in[4];
    const float* W2e = (const float*)d_in[5];
    const float* b2e = (const float*)d_in[6];
    const float* W1n = (const float*)d_in[7];
    const float* b1n = (const float*)d_in[8];
    const float* W2n = (const float*)d_in[9];
    const float* b2n = (const float*)d_in[10];

    float* out    = (float*)d_out;
    float* el_out = out;
    float* out_a  = out + (size_t)A_DIM * B_DIM * 16;
    float* out_b  = out_a + A_DIM * 32;

    float* ws     = (float*)d_ws;
    float* ha     = ws;                      // 16384
    float* hb     = ws + 16384;              // 16384
    float* suma_p = ws + 32768;              // 16 * 16384
    float* sumb_p = suma_p + 16 * 16384;     // 32 * 16384

    hipLaunchKernelGGL(prep_kernel, dim3(128), dim3(256), 0, stream,
                       na, nb, W1e, b1e, ha, hb);
    hipLaunchKernelGGL(edge_kernel, dim3(16, 32), dim3(1024), 0, stream,
                       E, W1e, W2e, b2e, ha, hb, el_out, suma_p, sumb_p);
    hipLaunchKernelGGL(node_kernel, dim3(256), dim3(256), 0, stream,
                       na, nb, suma_p, sumb_p, W1n, b1n, W2n, b2n, out_a, out_b);
}

// Round 4
// 59.483 us; speedup vs baseline: 1.1996x; 1.1996x over previous
//
#include <hip/hip_runtime.h>

#define A_DIM 1024
#define B_DIM 1024

typedef __attribute__((ext_vector_type(8))) short bfrag8;
typedef __attribute__((ext_vector_type(4))) float facc4;

__device__ __forceinline__ unsigned short f2bf(float f) {
    unsigned u = __float_as_uint(f);
    u = (u + 0x7FFFu + ((u >> 16) & 1u)) >> 16;
    return (unsigned short)u;
}
__device__ __forceinline__ unsigned cvtpk(float lo, float hi) {
    unsigned r;
    asm("v_cvt_pk_bf16_f32 %0, %1, %2" : "=v"(r) : "v"(lo), "v"(hi));
    return r;
}

// ---------------------------------------------------------------------------
// Kernel 1: ha[a][d] = b1e[d] + sum_k nodes_a[a][k] * Wa[k][d]
//           hb[b][d] =          sum_k nodes_b[b][k] * Wb[k][d]
// ---------------------------------------------------------------------------
__global__ __launch_bounds__(256) void prep_kernel(
    const float* __restrict__ na, const float* __restrict__ nb,
    const float* __restrict__ W1e, const float* __restrict__ b1e,
    float* __restrict__ ha, float* __restrict__ hb)
{
    int idx = blockIdx.x * 256 + threadIdx.x;   // 0..32767
    int half = idx >> 14;                       // 0 = a-side, 1 = b-side
    int r = (idx >> 4) & 1023;
    int d = idx & 15;
    const float* x = (half ? nb : na) + r * 32;
    const float* W = W1e + (half ? 64 * 16 : 32 * 16) + d;
    float acc = half ? 0.f : b1e[d];
    #pragma unroll
    for (int k = 0; k < 32; ++k) acc += x[k] * W[k * 16];
    (half ? hb : ha)[r * 16 + d] = acc;
}

// ---------------------------------------------------------------------------
// Kernel 2: fused edge MLP via MFMA, direct-global B-fragments, explicit
// 1-row-ahead double-buffered prefetch.
// Block = 1024 threads = 16 waves, grid (16 bg, 32 at). Wave w owns rows
// a = abase + w*2 + {0,1}; 4 mt tiles of 16 edges each.
// VGPR cap 128 via __launch_bounds__(1024,4): enough for 2x8 float4 E
// buffers + persistent fragments without spill, 1 block/CU.
// C/D layout: col = lane&15 (edge), row = (lane>>4)*4 + reg (d).
// A/B frag: 16-dim = lane&15, k = (lane>>4)*8 + t.
// ---------------------------------------------------------------------------
__global__ __launch_bounds__(1024, 4) void edge_kernel(
    const float* __restrict__ E, const float* __restrict__ W1e,
    const float* __restrict__ W2e, const float* __restrict__ b2e,
    const float* __restrict__ ha, const float* __restrict__ hb,
    float* __restrict__ el_out, float* __restrict__ suma_p,
    float* __restrict__ sumb_p)
{
    __shared__ __align__(16) float sb[8 * 64 * 16];   // 32 KB, sumb combine only
    const int tid  = threadIdx.x;
    const int lane = tid & 63;
    const int w    = tid >> 6;              // 0..15
    const int n    = lane & 15;             // edge-in-tile / weight d-col
    const int g    = lane >> 4;             // 0..3  k-chunk / d-row group
    const int bg   = blockIdx.x;            // 0..15
    const int at   = blockIdx.y;            // 0..31
    const int bbase = bg * 64;
    const int abase = at * 32;
    const int arow0 = abase + w * 2;

    // E double buffer: [row parity][mt*2 + (lo/hi)]
    float4 ebuf[2][8];

#define LOADROW(bi, arow)                                                      \
    {                                                                          \
        const float* base_ = E + ((size_t)(arow) * B_DIM + bbase) * 32;        \
        _Pragma("unroll")                                                      \
        for (int mt = 0; mt < 4; ++mt) {                                       \
            const float* ep_ = base_ + (mt * 16 + n) * 32 + g * 8;             \
            ebuf[bi][mt * 2]     = *(const float4*)ep_;                        \
            ebuf[bi][mt * 2 + 1] = *(const float4*)(ep_ + 4);                  \
        }                                                                      \
    }

    // prologue: row 0 loads in flight while we set up fragments
    LOADROW(0, arow0)

    // persistent fragments (weights transposed: A[m][k] = W[k][m])
    bfrag8 w1f, w2f;
    #pragma unroll
    for (int t = 0; t < 8; ++t) {
        w1f[t] = (short)f2bf(W1e[(g * 8 + t) * 16 + n]);
        w2f[t] = (g < 2) ? (short)f2bf(W2e[(g * 8 + t) * 16 + n]) : (short)0;
    }
    facc4 b2f = *(const facc4*)&b2e[g * 4];
    facc4 hbF[4];
    #pragma unroll
    for (int mt = 0; mt < 4; ++mt)
        hbF[mt] = *(const facc4*)&hb[(bbase + mt * 16 + n) * 16 + g * 4];
    facc4 haF[2];
    #pragma unroll
    for (int i = 0; i < 2; ++i)
        haF[i] = *(const facc4*)&ha[(arow0 + i) * 16 + g * 4];

    facc4 sumbA[4];
    #pragma unroll
    for (int mt = 0; mt < 4; ++mt) sumbA[mt] = facc4{0.f, 0.f, 0.f, 0.f};

#define COMPUTEROW(bi, i, arow)                                                \
    {                                                                          \
        facc4 ssum = facc4{0.f, 0.f, 0.f, 0.f};                                \
        _Pragma("unroll")                                                      \
        for (int mt = 0; mt < 4; ++mt) {                                       \
            float4 lo = ebuf[bi][mt * 2], hi = ebuf[bi][mt * 2 + 1];           \
            union { unsigned u[4]; bfrag8 s; } ef;                             \
            ef.u[0] = cvtpk(lo.x, lo.y); ef.u[1] = cvtpk(lo.z, lo.w);          \
            ef.u[2] = cvtpk(hi.x, hi.y); ef.u[3] = cvtpk(hi.z, hi.w);          \
            facc4 h = __builtin_amdgcn_mfma_f32_16x16x32_bf16(                 \
                w1f, ef.s, haF[i] + hbF[mt], 0, 0, 0);                         \
            h.x = fmaxf(h.x, 0.f); h.y = fmaxf(h.y, 0.f);                      \
            h.z = fmaxf(h.z, 0.f); h.w = fmaxf(h.w, 0.f);                      \
            const int sl = (n + g * 32) & 63;                                  \
            const int sh = (n + g * 32 + 16) & 63;                             \
            float v0 = __shfl(h.x, sl), v1 = __shfl(h.y, sl);                  \
            float v2 = __shfl(h.z, sl), v3 = __shfl(h.w, sl);                  \
            float u0 = __shfl(h.x, sh), u1 = __shfl(h.y, sh);                  \
            float u2 = __shfl(h.z, sh), u3 = __shfl(h.w, sh);                  \
            union { unsigned u[4]; bfrag8 s; } bb;                             \
            bb.u[0] = cvtpk(v0, v1); bb.u[1] = cvtpk(v2, v3);                  \
            bb.u[2] = cvtpk(u0, u1); bb.u[3] = cvtpk(u2, u3);                  \
            facc4 e = __builtin_amdgcn_mfma_f32_16x16x32_bf16(                 \
                w2f, bb.s, b2f, 0, 0, 0);                                      \
            e.x = fmaxf(e.x, 0.f); e.y = fmaxf(e.y, 0.f);                      \
            e.z = fmaxf(e.z, 0.f); e.w = fmaxf(e.w, 0.f);                      \
            *(facc4*)&el_out[((size_t)(arow) * B_DIM + bbase + mt * 16 + n)    \
                             * 16 + g * 4] = e;                                \
            sumbA[mt] += e;                                                    \
            ssum += e;                                                         \
        }                                                                      \
        _Pragma("unroll")                                                      \
        for (int m = 1; m <= 8; m <<= 1) {                                     \
            ssum.x += __shfl_xor(ssum.x, m);                                   \
            ssum.y += __shfl_xor(ssum.y, m);                                   \
            ssum.z += __shfl_xor(ssum.z, m);                                   \
            ssum.w += __shfl_xor(ssum.w, m);                                   \
        }                                                                      \
        if (n == 0)                                                            \
            *(facc4*)&suma_p[((size_t)bg * A_DIM + (arow)) * 16 + g * 4] = ssum; \
    }

    // pipeline: prefetch row 1 while computing row 0
    LOADROW(1, arow0 + 1)
    COMPUTEROW(0, 0, arow0)
    COMPUTEROW(1, 1, arow0 + 1)

#undef LOADROW
#undef COMPUTEROW

    // ---- combine sumb across 16 waves, two-stage, 32KB LDS ----
    __syncthreads();
    if (w >= 8) {
        #pragma unroll
        for (int mt = 0; mt < 4; ++mt)
            ((facc4*)sb)[((w - 8) * 64 + mt * 16 + n) * 4 + g] = sumbA[mt];
    }
    __syncthreads();
    if (w < 8) {
        #pragma unroll
        for (int mt = 0; mt < 4; ++mt) {
            sumbA[mt] += ((facc4*)sb)[(w * 64 + mt * 16 + n) * 4 + g];
            ((facc4*)sb)[(w * 64 + mt * 16 + n) * 4 + g] = sumbA[mt];
        }
    }
    __syncthreads();
    if (tid < 256) {
        const int bl = tid >> 2, q = tid & 3;
        facc4 s = facc4{0.f, 0.f, 0.f, 0.f};
        #pragma unroll
        for (int ww = 0; ww < 8; ++ww) s += ((facc4*)sb)[(ww * 64 + bl) * 4 + q];
        *(facc4*)&sumb_p[((size_t)at * B_DIM + bbase + bl) * 16 + q * 4] = s;
    }
}

// ---------------------------------------------------------------------------
// Kernel 3: node MLP for both sides, with inlined partial-sum reduction.
// ---------------------------------------------------------------------------
__global__ __launch_bounds__(256) void node_kernel(
    const float* __restrict__ na, const float* __restrict__ nb,
    const float* __restrict__ suma_p, const float* __restrict__ sumb_p,
    const float* __restrict__ W1n, const float* __restrict__ b1n,
    const float* __restrict__ W2n, const float* __restrict__ b2n,
    float* __restrict__ out_a, float* __restrict__ out_b)
{
    __shared__ float W1_s[48 * 32];
    __shared__ float W2_s[32 * 32];
    __shared__ float hid_s[8][32];
    __shared__ float sx_s[8][16];
    int tid = threadIdx.x;
    for (int i = tid; i < 1536; i += 256) W1_s[i] = W1n[i];
    for (int i = tid; i < 1024; i += 256) W2_s[i] = W2n[i];
    int rlocal = tid >> 5;
    int r = blockIdx.x * 8 + rlocal;
    int j = tid & 31;
    int isb = (r >= 1024);
    int rr = isb ? r - 1024 : r;
    if (j < 16) {
        const float* P = isb ? sumb_p : suma_p;
        int np = isb ? 32 : 16;
        float acc = 0.f;
        for (int t = 0; t < np; ++t) acc += P[(size_t)t * 16384 + rr * 16 + j];
        sx_s[rlocal][j] = acc;
    }
    __syncthreads();
    const float* nx = (isb ? nb : na) + rr * 32;
    float acc = b1n[j];
    #pragma unroll
    for (int k = 0; k < 32; ++k) acc += nx[k] * W1_s[k * 32 + j];
    #pragma unroll
    for (int k = 0; k < 16; ++k) acc += sx_s[rlocal][k] * W1_s[(32 + k) * 32 + j];
    hid_s[rlocal][j] = fmaxf(acc, 0.f);
    __syncthreads();
    float acc2 = b2n[j];
    #pragma unroll
    for (int k = 0; k < 32; ++k) acc2 += hid_s[rlocal][k] * W2_s[k * 32 + j];
    (isb ? out_b : out_a)[rr * 32 + j] = fmaxf(acc2, 0.f);
}

extern "C" void kernel_launch(void* const* d_in, const int* in_sizes, int n_in,
                              void* d_out, int out_size, void* d_ws, size_t ws_size,
                              hipStream_t stream)
{
    const float* E   = (const float*)d_in[0];
    const float* na  = (const float*)d_in[1];
    const float* nb  = (const float*)d_in[2];
    const float* W1e = (const float*)d_in[3];
    const float* b1e = (const float*)d_in[4];
    const float* W2e = (const float*)d_in[5];
    const float* b2e = (const float*)d_in[6];
    const float* W1n = (const float*)d_in[7];
    const float* b1n = (const float*)d_in[8];
    const float* W2n = (const float*)d_in[9];
    const float* b2n = (const float*)d_in[10];

    float* out    = (float*)d_out;
    float* el_out = out;
    float* out_a  = out + (size_t)A_DIM * B_DIM * 16;
    float* out_b  = out_a + A_DIM * 32;

    float* ws     = (float*)d_ws;
    float* ha     = ws;                      // 16384
    float* hb     = ws + 16384;              // 16384
    float* suma_p = ws + 32768;              // 16 * 16384
    float* sumb_p = suma_p + 16 * 16384;     // 32 * 16384

    hipLaunchKernelGGL(prep_kernel, dim3(128), dim3(256), 0, stream,
                       na, nb, W1e, b1e, ha, hb);
    hipLaunchKernelGGL(edge_kernel, dim3(16, 32), dim3(1024), 0, stream,
                       E, W1e, W2e, b2e, ha, hb, el_out, suma_p, sumb_p);
    hipLaunchKernelGGL(node_kernel, dim3(256), dim3(256), 0, stream,
                       na, nb, suma_p, sumb_p, W1n, b1n, W2n, b2n, out_a, out_b);
}